// Round 2
// baseline (405.354 us; speedup 1.0000x reference)
//
#include <hip/hip_runtime.h>

typedef unsigned short u16;
typedef unsigned int u32;
typedef __bf16 bf16x8 __attribute__((ext_vector_type(8)));
typedef float f32x4 __attribute__((ext_vector_type(4)));
typedef float f32x16 __attribute__((ext_vector_type(16)));

__device__ __forceinline__ float b2f(u16 u) { return __uint_as_float(((u32)u) << 16); }
__device__ __forceinline__ u16 f2b(float f) {
  u32 u = __float_as_uint(f);
  u += 0x7fffu + ((u >> 16) & 1u);   // round-to-nearest-even
  return (u16)(u >> 16);
}

// async global->LDS, 16B per lane; lds dest = wave-uniform base + lane*16
__device__ __forceinline__ void gll16(const u16* g, u16* l) {
  __builtin_amdgcn_global_load_lds(
      (const __attribute__((address_space(1))) void*)g,
      (__attribute__((address_space(3))) void*)l, 16, 0, 0);
}

// load 4 consecutive elements, dtype-polymorphic (uniform branch)
__device__ __forceinline__ float4 load4(const void* p, size_t idx, bool f32) {
  if (f32) return *(const float4*)((const float*)p + idx);
  ushort4 u = *(const ushort4*)((const u16*)p + idx);
  return make_float4(b2f(u.x), b2f(u.y), b2f(u.z), b2f(u.w));
}

// ---------------------------------------------------------------- dtype sniff
__global__ __launch_bounds__(256) void detect_kernel(const u16* __restrict__ sig,
                                                     int* __restrict__ flag) {
  __shared__ int cnt;
  if (threadIdx.x == 0) cnt = 0;
  __syncthreads();
  int c = 0;
  for (int i = threadIdx.x; i < 16384; i += 256) {
    u16 v = sig[i];
    c += ((v & 0x7F80u) == 0x7F80u) ? 1 : 0;
  }
  atomicAdd(&cnt, c);
  __syncthreads();
  if (threadIdx.x == 0) *flag = (cnt >= 8) ? 1 : 0;
}

// ---------------------------------------------------------------- LN + var-prop
__global__ __launch_bounds__(256) void ln_prep_kernel(
    const int* __restrict__ flag,
    const void* __restrict__ mu, const void* __restrict__ sigma,
    const void* __restrict__ gamma, const void* __restrict__ beta,
    u16* __restrict__ mu_n, u16* __restrict__ a1sg)
{
  __shared__ float ps[4], pq[4];
  const bool f32 = (*flag != 0);
  const int t = threadIdx.x;
  const int wv = t >> 6, lane = t & 63;
  const size_t base = (size_t)blockIdx.x * 1024 + (size_t)t * 4;
  float4 xm = load4(mu, base, f32);
  float4 xs = load4(sigma, base, f32);
  float x0 = xm.x, x1 = xm.y, x2 = xm.z, x3 = xm.w;
  float s0 = xs.x, s1 = xs.y, s2 = xs.z, s3 = xs.w;

  float sv = x0 + x1 + x2 + x3;
  float qv = x0*x0 + x1*x1 + x2*x2 + x3*x3;
  #pragma unroll
  for (int off = 32; off > 0; off >>= 1) {
    sv += __shfl_xor(sv, off, 64);
    qv += __shfl_xor(qv, off, 64);
  }
  if (lane == 0) { ps[wv] = sv; pq[wv] = qv; }
  __syncthreads();
  float sum = ps[0] + ps[1] + ps[2] + ps[3];
  float ssq = pq[0] + pq[1] + pq[2] + pq[3];

  float mean = sum * (1.0f / 1024.0f);
  float var  = ssq * (1.0f / 1024.0f) - mean * mean;
  float inv  = 1.0f / sqrtf(var + 1e-5f);
  float inv2 = inv * inv;

  float4 g4 = load4(gamma, (size_t)t * 4, f32);
  float4 b4 = load4(beta, (size_t)t * 4, f32);

  float m0 = (x0 - mean) * inv * g4.x + b4.x;
  float m1 = (x1 - mean) * inv * g4.y + b4.y;
  float m2 = (x2 - mean) * inv * g4.z + b4.z;
  float m3 = (x3 - mean) * inv * g4.w + b4.w;
  float v0 = s0 * g4.x * g4.x * inv2;
  float v1 = s1 * g4.y * g4.y * inv2;
  float v2 = s2 * g4.z * g4.z * inv2;
  float v3 = s3 * g4.w * g4.w * inv2;

  ushort4 omu = { f2b(m0), f2b(m1), f2b(m2), f2b(m3) };
  ushort4 oa1 = { f2b(m0*m0 + v0), f2b(m1*m1 + v1), f2b(m2*m2 + v2), f2b(m3*m3 + v3) };
  ushort4 osg = { f2b(v0), f2b(v1), f2b(v2), f2b(v3) };
  *(ushort4*)(mu_n + base) = omu;
  size_t r2 = (size_t)blockIdx.x * 2048 + (size_t)t * 4;
  *(ushort4*)(a1sg + r2) = oa1;
  *(ushort4*)(a1sg + r2 + 1024) = osg;
}

// ---------------------------------------------------------------- weight prep (fused)
__global__ __launch_bounds__(256) void wprep_kernel(
    const int* __restrict__ flag,
    const void* __restrict__ wq_mu, const void* __restrict__ wq_sraw,
    u16* __restrict__ q_bf, u16* __restrict__ q_s2,
    const void* __restrict__ wo_mu, const void* __restrict__ wo_sraw,
    u16* __restrict__ o_bf, u16* __restrict__ o_s2, int nq)
{
  const bool f32 = (*flag != 0);
  size_t idx = ((size_t)blockIdx.x * 256 + threadIdx.x) * 4;
  const void *wmu, *wsr; u16 *obf, *os2;
  if (idx < (size_t)nq) { wmu = wq_mu; wsr = wq_sraw; obf = q_bf; os2 = q_s2; }
  else { idx -= nq; wmu = wo_mu; wsr = wo_sraw; obf = o_bf; os2 = o_s2; }
  int row = (int)(idx >> 10), k = (int)(idx & 1023);
  float4 m4 = load4(wmu, idx, f32);
  float4 s4 = load4(wsr, idx, f32);
  float m[4] = { m4.x, m4.y, m4.z, m4.w };
  float s[4] = { s4.x, s4.y, s4.z, s4.w };
  ushort4 ob, os, oq;
  u16* obp = (u16*)&ob; u16* osp = (u16*)&os; u16* oqp = (u16*)&oq;
  #pragma unroll
  for (int i = 0; i < 4; ++i) {
    float sp = (s[i] > 15.f) ? s[i] : log1pf(__expf(s[i]));
    obp[i] = f2b(m[i]);
    osp[i] = f2b(sp);
    oqp[i] = f2b(m[i] * m[i]);
  }
  *(ushort4*)(obf + idx) = ob;
  size_t r2 = (size_t)row * 2048 + k;
  *(ushort4*)(os2 + r2) = os;
  *(ushort4*)(os2 + r2 + 1024) = oq;
}

// ---------------------------------------------------------------- paired GEMM (old 128^2, kept for output GEMM)
template<bool DYN>
__global__ __launch_bounds__(256, 4) void gemm_pair_kernel(
    const u16* __restrict__ A0, const u16* __restrict__ B0, int K0, void* C0, size_t ob0,
    const u16* __restrict__ A1, const u16* __restrict__ B1, int K1, void* C1, size_t ob1,
    int split, int N, const int* __restrict__ flag)
{
  __shared__ u16 lA[128 * 64];
  __shared__ u16 lB[128 * 64];
  const int t = threadIdx.x;
  int bx = blockIdx.x;
  const u16 *A, *B; void* C; size_t obase; int K;
  if (bx < split) { A = A0; B = B0; K = K0; C = C0; obase = ob0; }
  else { bx -= split; A = A1; B = B1; K = K1; C = C1; obase = ob1; }

  const int n0 = bx * 128, m0 = blockIdx.y * 128;
  const int lane = t & 63, wave = t >> 6;
  const int wr = (wave >> 1) * 64, wc = (wave & 1) * 64;
  const int m31 = lane & 31, h5 = lane >> 5;
  const int mx = m31 & 7;

  const int srow = t >> 3;
  const int gseg = (t & 7) ^ (srow & 7);

  f32x16 acc[2][2];
  #pragma unroll
  for (int i = 0; i < 2; ++i)
    #pragma unroll
    for (int j = 0; j < 2; ++j)
      #pragma unroll
      for (int r = 0; r < 16; ++r) acc[i][j][r] = 0.f;

  for (int k0 = 0; k0 < K; k0 += 64) {
    __syncthreads();
    #pragma unroll
    for (int rep = 0; rep < 4; ++rep) {
      gll16(A + (size_t)(m0 + srow + rep * 32) * K + k0 + gseg * 8,
            lA + rep * 2048 + wave * 512);
      gll16(B + (size_t)(n0 + srow + rep * 32) * K + k0 + gseg * 8,
            lB + rep * 2048 + wave * 512);
    }
    __syncthreads();
    #pragma unroll
    for (int ks = 0; ks < 4; ++ks) {
      const int seg = ks * 2 + h5;
      bf16x8 af[2], bfr[2];
      #pragma unroll
      for (int tm = 0; tm < 2; ++tm)
        af[tm] = *(const bf16x8*)&lA[(wr + tm * 32 + m31) * 64 + (seg ^ mx) * 8];
      #pragma unroll
      for (int tn = 0; tn < 2; ++tn)
        bfr[tn] = *(const bf16x8*)&lB[(wc + tn * 32 + m31) * 64 + (seg ^ mx) * 8];
      #pragma unroll
      for (int tm = 0; tm < 2; ++tm)
        #pragma unroll
        for (int tn = 0; tn < 2; ++tn)
          acc[tm][tn] = __builtin_amdgcn_mfma_f32_32x32x16_bf16(af[tm], bfr[tn], acc[tm][tn], 0, 0, 0);
    }
  }

  const bool of32 = DYN && (*flag != 0);
  #pragma unroll
  for (int tm = 0; tm < 2; ++tm)
    #pragma unroll
    for (int tn = 0; tn < 2; ++tn) {
      int colb = n0 + wc + tn * 32 + m31;
      #pragma unroll
      for (int r = 0; r < 16; ++r) {
        int row = m0 + wr + tm * 32 + (r & 3) + 8 * (r >> 2) + 4 * h5;
        float v = acc[tm][tn][r];
        size_t off = obase + (size_t)row * N + colb;
        if (DYN) {
          if (of32) ((float*)C)[off] = v;
          else      ((u16*)C)[off] = f2b(v);
        } else {
          ((u16*)C)[off] = f2b(v);
        }
      }
    }
}

// ---------------------------------------------------------------- paired GEMM (256^2, 8-phase counted-vmcnt)
// BM=BN=256, BK=64. 512 thr = 8 waves (2M x 4N), per-wave 128x64 out, 16x16x32 MFMA.
// LDS 128KiB: [2 buf][2 half][128][64] for A and B. One half-tile staged/phase:
//   P1: A-h0(T+1)  P2: A-h1(T+1)  P3: B-h0(T+2)  P4: B-h1(T+2)
// -> every half-tile has >=3 MFMA phases in flight before its ds_read.
// vmcnt(4) once per K-tile (leaves the newest B pair in flight); vmcnt(0) only
// entering the last tile. Raw s_barrier + sched_barrier pins (no __syncthreads drain).
#define SB __builtin_amdgcn_sched_barrier(0)
#define BARRIER do { SB; __builtin_amdgcn_s_barrier(); SB; } while (0)

__global__ __launch_bounds__(512, 2) void gemm8_pair_kernel(
    const u16* __restrict__ A0, const u16* __restrict__ B0, int K0, u16* __restrict__ C0,
    const u16* __restrict__ A1, const u16* __restrict__ B1, int K1, u16* __restrict__ C1,
    int split, int N)
{
  __shared__ u16 lA[2 * 2 * 128 * 64];
  __shared__ u16 lB[2 * 2 * 128 * 64];
  const int t = threadIdx.x;
  int bx = blockIdx.x;
  const u16 *A, *B; u16* C; int K;
  if (bx < split) { A = A0; B = B0; K = K0; C = C0; }
  else { bx -= split; A = A1; B = B1; K = K1; C = C1; }
  const int NT = K >> 6;
  const int n0 = bx * 256, m0 = blockIdx.y * 256;
  const int lane = t & 63, wave = t >> 6;
  const int wm = wave >> 2, wn = wave & 3;
  const int ml = lane & 15, qd = lane >> 4, mx = ml & 7;

  // stage one 128x64 half-tile: 2 x gll16 per wave, pre-swizzled global source
  auto stg = [&](const u16* __restrict__ X, int row0, int k0, u16* ldsHalf) {
    #pragma unroll
    for (int j = 0; j < 2; ++j) {
      int r = (wave * 2 + j) * 8 + (lane >> 3);
      int seg = (lane & 7) ^ ((lane >> 3) & 7);
      gll16(X + (size_t)(row0 + r) * K + k0 + seg * 8,
            ldsHalf + (wave * 2 + j) * 512);
    }
  };

  // per-lane read bases (u16 index); + buf*16384 + frag*1024 + swizzled seg*8
  const u16* rdA = lA + (wm * 128 + ml) * 64;
  const u16* rdB = lB + ((wn >> 1) * 128 + (wn & 1) * 64 + ml) * 64;

  f32x4 acc[8][4];
  #pragma unroll
  for (int i = 0; i < 8; ++i)
    #pragma unroll
    for (int j = 0; j < 4; ++j)
      acc[i][j] = (f32x4){0.f, 0.f, 0.f, 0.f};

  bf16x8 fa[4][2];        // current A quadrant: 4 m-frags x 2 ksub
  bf16x8 fb[2][2][2];     // [n-half][2 n-frags][2 ksub] (both halves live)

  // prologue: tile0 (all 4 half-tiles) + tile1 B halves
  stg(A, m0,       0,  lA);
  stg(A, m0 + 128, 0,  lA + 8192);
  stg(B, n0,       0,  lB);
  stg(B, n0 + 128, 0,  lB + 8192);
  if (NT > 1) {
    stg(B, n0,       64, lB + 16384);
    stg(B, n0 + 128, 64, lB + 16384 + 8192);
  }
  SB;
  asm volatile("s_waitcnt vmcnt(4)" ::: "memory");
  BARRIER;

  for (int T = 0; T < NT; ++T) {
    const int bo  = (T & 1) * 16384;
    const int bon = bo ^ 16384;
    const int kn  = (T + 1) * 64;
    const int kn2 = (T + 2) * 64;

    // ---------------- P1: read fa(m0..3), fb[0]; stage A-h0(T+1); mfma (0,0)
    #pragma unroll
    for (int i = 0; i < 4; ++i)
      #pragma unroll
      for (int ks = 0; ks < 2; ++ks)
        fa[i][ks] = *(const bf16x8*)&rdA[bo + i * 1024 + ((ks * 4 + qd) ^ mx) * 8];
    #pragma unroll
    for (int j = 0; j < 2; ++j)
      #pragma unroll
      for (int ks = 0; ks < 2; ++ks)
        fb[0][j][ks] = *(const bf16x8*)&rdB[bo + j * 1024 + ((ks * 4 + qd) ^ mx) * 8];
    if (T + 1 < NT) stg(A, m0, kn, lA + bon);
    BARRIER;
    __builtin_amdgcn_s_setprio(1);
    #pragma unroll
    for (int i = 0; i < 4; ++i)
      #pragma unroll
      for (int j = 0; j < 2; ++j)
        #pragma unroll
        for (int ks = 0; ks < 2; ++ks)
          acc[i][j] = __builtin_amdgcn_mfma_f32_16x16x32_bf16(fa[i][ks], fb[0][j][ks], acc[i][j], 0, 0, 0);
    __builtin_amdgcn_s_setprio(0);
    BARRIER;

    // ---------------- P2: read fb[1]; stage A-h1(T+1); mfma (0,1)
    #pragma unroll
    for (int j = 0; j < 2; ++j)
      #pragma unroll
      for (int ks = 0; ks < 2; ++ks)
        fb[1][j][ks] = *(const bf16x8*)&rdB[bo + (2 + j) * 1024 + ((ks * 4 + qd) ^ mx) * 8];
    if (T + 1 < NT) stg(A, m0 + 128, kn, lA + bon + 8192);
    BARRIER;
    __builtin_amdgcn_s_setprio(1);
    #pragma unroll
    for (int i = 0; i < 4; ++i)
      #pragma unroll
      for (int j = 0; j < 2; ++j)
        #pragma unroll
        for (int ks = 0; ks < 2; ++ks)
          acc[i][2 + j] = __builtin_amdgcn_mfma_f32_16x16x32_bf16(fa[i][ks], fb[1][j][ks], acc[i][2 + j], 0, 0, 0);
    __builtin_amdgcn_s_setprio(0);
    BARRIER;

    // ---------------- P3: read fa(m4..7); stage B-h0(T+2); mfma (1,1)
    #pragma unroll
    for (int i = 0; i < 4; ++i)
      #pragma unroll
      for (int ks = 0; ks < 2; ++ks)
        fa[i][ks] = *(const bf16x8*)&rdA[bo + (4 + i) * 1024 + ((ks * 4 + qd) ^ mx) * 8];
    if (T + 2 < NT) stg(B, n0, kn2, lB + bo);
    BARRIER;
    __builtin_amdgcn_s_setprio(1);
    #pragma unroll
    for (int i = 0; i < 4; ++i)
      #pragma unroll
      for (int j = 0; j < 2; ++j)
        #pragma unroll
        for (int ks = 0; ks < 2; ++ks)
          acc[4 + i][2 + j] = __builtin_amdgcn_mfma_f32_16x16x32_bf16(fa[i][ks], fb[1][j][ks], acc[4 + i][2 + j], 0, 0, 0);
    __builtin_amdgcn_s_setprio(0);
    BARRIER;

    // ---------------- P4: stage B-h1(T+2); mfma (1,0); counted vmcnt
    if (T + 2 < NT) stg(B, n0 + 128, kn2, lB + bo + 8192);
    BARRIER;
    __builtin_amdgcn_s_setprio(1);
    #pragma unroll
    for (int i = 0; i < 4; ++i)
      #pragma unroll
      for (int j = 0; j < 2; ++j)
        #pragma unroll
        for (int ks = 0; ks < 2; ++ks)
          acc[4 + i][j] = __builtin_amdgcn_mfma_f32_16x16x32_bf16(fa[i][ks], fb[0][j][ks], acc[4 + i][j], 0, 0, 0);
    __builtin_amdgcn_s_setprio(0);
    SB;
    if (T + 2 < NT) asm volatile("s_waitcnt vmcnt(4)" ::: "memory");
    else            asm volatile("s_waitcnt vmcnt(0)" ::: "memory");
    BARRIER;
  }

  // epilogue: C row = m0 + wm*128 + mf*16 + qd*4 + r, col = n0 + wn*64 + nf*16 + ml
  #pragma unroll
  for (int mf = 0; mf < 8; ++mf)
    #pragma unroll
    for (int nf = 0; nf < 4; ++nf)
      #pragma unroll
      for (int r = 0; r < 4; ++r) {
        int row = m0 + wm * 128 + mf * 16 + qd * 4 + r;
        int col = n0 + wn * 64 + nf * 16 + ml;
        C[(size_t)row * N + col] = f2b(acc[mf][nf][r]);
      }
}

// ---------------------------------------------------------------- attention pass 1
__global__ __launch_bounds__(256) void attn_pass1(
    const u16* __restrict__ qkv_mu, float* __restrict__ invl)
{
  __shared__ u16 lK[128 * 72];
  const int t = threadIdx.x;
  const int wv = t >> 6, lane = t & 63;
  const int ml = lane & 15, qd = lane >> 4;
  const int bh = blockIdx.y;
  const int b = bh >> 4, h = bh & 15;
  const size_t rowbase = (size_t)b * 1024 * 3072;
  const int i0 = blockIdx.x * 64;
  const int qcol = h * 64, kcol = 1024 + h * 64;
  const int qrow = wv * 16;

  bf16x8 aQm[2];
  #pragma unroll
  for (int ks = 0; ks < 2; ++ks)
    aQm[ks] = *(const bf16x8*)(qkv_mu + rowbase +
        (size_t)(i0 + qrow + ml) * 3072 + qcol + ks * 32 + qd * 8);

  float lsum[4] = {0.f, 0.f, 0.f, 0.f};

  for (int j0 = 0; j0 < 1024; j0 += 128) {
    __syncthreads();
    #pragma unroll
    for (int rep = 0; rep < 4; ++rep) {
      int c = t + rep * 256;
      int row = c >> 3, seg = c & 7;
      *(uint4*)&lK[row * 72 + seg * 8] =
          *(const uint4*)(qkv_mu + rowbase + (size_t)(j0 + row) * 3072 + kcol + seg * 8);
    }
    __syncthreads();
    #pragma unroll
    for (int tj = 0; tj < 8; ++tj) {
      bf16x8 b0 = *(const bf16x8*)&lK[(tj * 16 + ml) * 72 + qd * 8];
      bf16x8 b1 = *(const bf16x8*)&lK[(tj * 16 + ml) * 72 + 32 + qd * 8];
      f32x4 s = (f32x4){0.f, 0.f, 0.f, 0.f};
      s = __builtin_amdgcn_mfma_f32_16x16x32_bf16(aQm[0], b0, s, 0, 0, 0);
      s = __builtin_amdgcn_mfma_f32_16x16x32_bf16(aQm[1], b1, s, 0, 0, 0);
      #pragma unroll
      for (int r = 0; r < 4; ++r) lsum[r] += __expf(s[r] * 0.125f);
    }
  }
  #pragma unroll
  for (int r = 0; r < 4; ++r) {
    float l = lsum[r];
    #pragma unroll
    for (int xo = 1; xo < 16; xo <<= 1) l += __shfl_xor(l, xo, 64);
    if (ml == 0)
      invl[(size_t)bh * 1024 + i0 + qrow + qd * 4 + r] = 1.0f / l;
  }
}

// ---------------------------------------------------------------- attention pass 2
__global__ __launch_bounds__(512, 4) void attn_pass2(
    const u16* __restrict__ qkv_mu, const u16* __restrict__ qkv_sg,
    const float* __restrict__ invl,
    u16* __restrict__ o_mu, u16* __restrict__ a1sgo)
{
  __shared__ u16 lKW[128 * 72];
  __shared__ u16 lV[128 * 72];
  __shared__ u16 lP[128 * 72];
  __shared__ u16 lW[128 * 72];

  const int t = threadIdx.x;
  const int wv = t >> 6, lane = t & 63;
  const int ml = lane & 15, qd = lane >> 4;
  const int bh = blockIdx.y;
  const int b = bh >> 4, h = bh & 15;
  const size_t rowbase = (size_t)b * 1024 * 3072;
  const int i0 = blockIdx.x * 128;
  const int qcol = h * 64, kcol = 1024 + h * 64, vcol = 2048 + h * 64;
  const int qrow = wv * 16;

  bf16x8 aQm[2], aQs[2];
  #pragma unroll
  for (int ks = 0; ks < 2; ++ks) {
    size_t ga = rowbase + (size_t)(i0 + qrow + ml) * 3072 + qcol + ks * 32 + qd * 8;
    aQm[ks] = *(const bf16x8*)(qkv_mu + ga);
    aQs[ks] = *(const bf16x8*)(qkv_sg + ga);
  }

  float lacc[4];
  #pragma unroll
  for (int r = 0; r < 4; ++r)
    lacc[r] = invl[(size_t)bh * 1024 + i0 + qrow + qd * 4 + r];

  f32x4 accm[4], accs[4];
  #pragma unroll
  for (int tj = 0; tj < 4; ++tj) {
    accm[tj] = (f32x4){0.f, 0.f, 0.f, 0.f};
    accs[tj] = (f32x4){0.f, 0.f, 0.f, 0.f};
  }

  for (int j0 = 0; j0 < 1024; j0 += 64) {
    __syncthreads();   // prev PV reads done before restaging
    #pragma unroll
    for (int rep = 0; rep < 2; ++rep) {
      int c = t + rep * 512;
      int row = c >> 3, seg = c & 7;
      const u16* src = (row < 64) ? qkv_mu : qkv_sg;
      int rr = row & 63;
      *(uint4*)&lKW[row * 72 + seg * 8] =
          *(const uint4*)(src + rowbase + (size_t)(j0 + rr) * 3072 + kcol + seg * 8);
    }
    {
      int buf = t >> 8, rem = t & 255;
      int db = rem >> 4, tb = rem & 15;
      const u16* src = buf ? qkv_sg : qkv_mu;
      ushort4 vals[4];
      #pragma unroll
      for (int i = 0; i < 4; ++i)
        vals[i] = *(const ushort4*)(src + rowbase + (size_t)(j0 + tb * 4 + i) * 3072 + vcol + db * 4);
      #pragma unroll
      for (int k = 0; k < 4; ++k) {
        ushort4 o;
        u16* op = (u16*)&o;
        const u16* v0 = (const u16*)&vals[0];
        const u16* v1 = (const u16*)&vals[1];
        const u16* v2 = (const u16*)&vals[2];
        const u16* v3 = (const u16*)&vals[3];
        op[0] = v0[k]; op[1] = v1[k]; op[2] = v2[k]; op[3] = v3[k];
        *(ushort4*)&lV[(buf * 64 + db * 4 + k) * 72 + tb * 4] = o;
      }
    }
    __syncthreads();

    f32x4 sm[4], ss[4];
    #pragma unroll
    for (int tj = 0; tj < 4; ++tj) {
      bf16x8 bm0 = *(const bf16x8*)&lKW[(tj * 16 + ml) * 72 + qd * 8];
      bf16x8 bm1 = *(const bf16x8*)&lKW[(tj * 16 + ml) * 72 + 32 + qd * 8];
      bf16x8 bs0 = *(const bf16x8*)&lKW[(64 + tj * 16 + ml) * 72 + qd * 8];
      bf16x8 bs1 = *(const bf16x8*)&lKW[(64 + tj * 16 + ml) * 72 + 32 + qd * 8];
      f32x4 s = (f32x4){0.f, 0.f, 0.f, 0.f};
      s = __builtin_amdgcn_mfma_f32_16x16x32_bf16(aQm[0], bm0, s, 0, 0, 0);
      s = __builtin_amdgcn_mfma_f32_16x16x32_bf16(aQm[1], bm1, s, 0, 0, 0);
      sm[tj] = s;
      f32x4 s2 = (f32x4){0.f, 0.f, 0.f, 0.f};
      s2 = __builtin_amdgcn_mfma_f32_16x16x32_bf16(aQs[0], bs0, s2, 0, 0, 0);
      s2 = __builtin_amdgcn_mfma_f32_16x16x32_bf16(aQs[1], bs1, s2, 0, 0, 0);
      ss[tj] = s2;
    }

    #pragma unroll
    for (int tj = 0; tj < 4; ++tj)
      #pragma unroll
      for (int r = 0; r < 4; ++r) {
        float p = __expf(sm[tj][r] * 0.125f) * lacc[r];
        float jp = p * (1.0f - p);
        float w = jp * jp * (ss[tj][r] * 0.125f);
        int row = qrow + qd * 4 + r;
        lP[row * 72 + tj * 16 + ml] = f2b(p);
        lW[row * 72 + tj * 16 + ml] = f2b(w);
      }
    __syncthreads();

    bf16x8 ap[2], aw[2];
    #pragma unroll
    for (int ks = 0; ks < 2; ++ks) {
      ap[ks] = *(const bf16x8*)&lP[(qrow + ml) * 72 + ks * 32 + qd * 8];
      aw[ks] = *(const bf16x8*)&lW[(qrow + ml) * 72 + ks * 32 + qd * 8];
    }
    #pragma unroll
    for (int tj = 0; tj < 4; ++tj) {
      bf16x8 vm0 = *(const bf16x8*)&lV[(tj * 16 + ml) * 72 + qd * 8];
      bf16x8 vm1 = *(const bf16x8*)&lV[(tj * 16 + ml) * 72 + 32 + qd * 8];
      bf16x8 vs0 = *(const bf16x8*)&lV[(64 + tj * 16 + ml) * 72 + qd * 8];
      bf16x8 vs1 = *(const bf16x8*)&lV[(64 + tj * 16 + ml) * 72 + 32 + qd * 8];
      accm[tj] = __builtin_amdgcn_mfma_f32_16x16x32_bf16(ap[0], vm0, accm[tj], 0, 0, 0);
      accm[tj] = __builtin_amdgcn_mfma_f32_16x16x32_bf16(ap[1], vm1, accm[tj], 0, 0, 0);
      accs[tj] = __builtin_amdgcn_mfma_f32_16x16x32_bf16(aw[0], vs0, accs[tj], 0, 0, 0);
      accs[tj] = __builtin_amdgcn_mfma_f32_16x16x32_bf16(aw[1], vs1, accs[tj], 0, 0, 0);
    }
  }

  // epilogue: o_mu [row][1024]; a1sgo [row][2048] = [mu^2+sg | sg]
  #pragma unroll
  for (int tj = 0; tj < 4; ++tj)
    #pragma unroll
    for (int r = 0; r < 4; ++r) {
      int row = i0 + qrow + qd * 4 + r;
      int col = h * 64 + tj * 16 + ml;
      size_t rowg = (size_t)b * 1024 + row;
      float om = accm[tj][r], os = accs[tj][r];
      o_mu[rowg * 1024 + col] = f2b(om);
      size_t r2 = rowg * 2048 + col;
      a1sgo[r2] = f2b(fmaf(om, om, os));
      a1sgo[r2 + 1024] = f2b(os);
    }
}

// ---------------------------------------------------------------- launch
extern "C" void kernel_launch(void* const* d_in, const int* in_sizes, int n_in,
                              void* d_out, int out_size, void* d_ws, size_t ws_size,
                              hipStream_t stream)
{
  (void)in_sizes; (void)n_in; (void)out_size; (void)ws_size;
  const void* mu        = d_in[0];
  const void* sigma     = d_in[1];
  const void* gamma     = d_in[2];
  const void* beta      = d_in[3];
  const void* wqkv_mu   = d_in[4];
  const void* wqkv_sraw = d_in[5];
  const void* wout_mu   = d_in[6];
  const void* wout_sraw = d_in[7];

  u16* ws = (u16*)d_ws;
  const size_t R = 4096;  // B*N
  u16* mu_n   = ws;                        // R*1024, reused as mu_o
  u16* a1sg   = mu_n + R * 1024;           // R*2048 [A1|sgn], reused as a1sgo
  u16* wq_bf  = a1sg + R * 2048;           // 3072*1024
  u16* wqs2   = wq_bf + 3072 * 1024;       // 3072*2048 [Wsig|Wmu^2]
  u16* wo_bf  = wqs2 + 3072 * 2048;        // 1024*1024
  u16* wos2   = wo_bf + 1024 * 1024;       // 1024*2048
  u16* mu_qkv = wos2 + 1024 * 2048;        // R*3072
  u16* sg_qkv = mu_qkv + R * 3072;         // R*3072
  int* flag   = (int*)(sg_qkv + R * 3072);
  float* invl = (float*)(flag + 16);       // 64*1024 floats

  u16* mu_o  = mu_n;
  u16* a1sgo = a1sg;

  detect_kernel<<<1, 256, 0, stream>>>((const u16*)sigma, flag);
  ln_prep_kernel<<<4096, 256, 0, stream>>>(flag, mu, sigma, gamma, beta, mu_n, a1sg);
  wprep_kernel<<<(4 * 1024 * 1024) / 1024, 256, 0, stream>>>(
      flag, wqkv_mu, wqkv_sraw, wq_bf, wqs2,
      wout_mu, wout_sraw, wo_bf, wos2, 3072 * 1024);

  // merged QKV GEMMs (256^2 8-phase): mu (K=1024) + sigma (K=2048), N=3072
  gemm8_pair_kernel<<<dim3(24, 16), 512, 0, stream>>>(
      mu_n, wq_bf, 1024, mu_qkv,
      a1sg, wqs2, 2048, sg_qkv,
      12, 3072);

  attn_pass1<<<dim3(16, 64), 256, 0, stream>>>(mu_qkv, invl);
  attn_pass2<<<dim3(8, 64), 512, 0, stream>>>(mu_qkv, sg_qkv, invl, mu_o, a1sgo);

  // merged output GEMMs (old 128^2): mu (K=1024) + sigma (K=2048), N=1024
  gemm_pair_kernel<true><<<dim3(16, 32), 256, 0, stream>>>(
      mu_o, wo_bf, 1024, d_out, 0,
      a1sgo, wos2, 2048, d_out, R * 1024,
      8, 1024, flag);
}

// Round 3
// 389.033 us; speedup vs baseline: 1.0420x; 1.0420x over previous
//
#include <hip/hip_runtime.h>

typedef unsigned short u16;
typedef unsigned int u32;
typedef __bf16 bf16x8 __attribute__((ext_vector_type(8)));
typedef float f32x4 __attribute__((ext_vector_type(4)));
typedef float f32x16 __attribute__((ext_vector_type(16)));

__device__ __forceinline__ float b2f(u16 u) { return __uint_as_float(((u32)u) << 16); }
__device__ __forceinline__ u16 f2b(float f) {
  u32 u = __float_as_uint(f);
  u += 0x7fffu + ((u >> 16) & 1u);   // round-to-nearest-even
  return (u16)(u >> 16);
}

// async global->LDS, 16B per lane; lds dest = wave-uniform base + lane*16
__device__ __forceinline__ void gll16(const u16* g, u16* l) {
  __builtin_amdgcn_global_load_lds(
      (const __attribute__((address_space(1))) void*)g,
      (__attribute__((address_space(3))) void*)l, 16, 0, 0);
}

// load 4 consecutive elements, dtype-polymorphic (uniform branch)
__device__ __forceinline__ float4 load4(const void* p, size_t idx, bool f32) {
  if (f32) return *(const float4*)((const float*)p + idx);
  ushort4 u = *(const ushort4*)((const u16*)p + idx);
  return make_float4(b2f(u.x), b2f(u.y), b2f(u.z), b2f(u.w));
}

// ---------------------------------------------------------------- dtype sniff
__global__ __launch_bounds__(256) void detect_kernel(const u16* __restrict__ sig,
                                                     int* __restrict__ flag) {
  __shared__ int cnt;
  if (threadIdx.x == 0) cnt = 0;
  __syncthreads();
  int c = 0;
  for (int i = threadIdx.x; i < 16384; i += 256) {
    u16 v = sig[i];
    c += ((v & 0x7F80u) == 0x7F80u) ? 1 : 0;
  }
  atomicAdd(&cnt, c);
  __syncthreads();
  if (threadIdx.x == 0) *flag = (cnt >= 8) ? 1 : 0;
}

// ---------------------------------------------------------------- LN + var-prop
__global__ __launch_bounds__(256) void ln_prep_kernel(
    const int* __restrict__ flag,
    const void* __restrict__ mu, const void* __restrict__ sigma,
    const void* __restrict__ gamma, const void* __restrict__ beta,
    u16* __restrict__ mu_n, u16* __restrict__ a1sg)
{
  __shared__ float ps[4], pq[4];
  const bool f32 = (*flag != 0);
  const int t = threadIdx.x;
  const int wv = t >> 6, lane = t & 63;
  const size_t base = (size_t)blockIdx.x * 1024 + (size_t)t * 4;
  float4 xm = load4(mu, base, f32);
  float4 xs = load4(sigma, base, f32);
  float x0 = xm.x, x1 = xm.y, x2 = xm.z, x3 = xm.w;
  float s0 = xs.x, s1 = xs.y, s2 = xs.z, s3 = xs.w;

  float sv = x0 + x1 + x2 + x3;
  float qv = x0*x0 + x1*x1 + x2*x2 + x3*x3;
  #pragma unroll
  for (int off = 32; off > 0; off >>= 1) {
    sv += __shfl_xor(sv, off, 64);
    qv += __shfl_xor(qv, off, 64);
  }
  if (lane == 0) { ps[wv] = sv; pq[wv] = qv; }
  __syncthreads();
  float sum = ps[0] + ps[1] + ps[2] + ps[3];
  float ssq = pq[0] + pq[1] + pq[2] + pq[3];

  float mean = sum * (1.0f / 1024.0f);
  float var  = ssq * (1.0f / 1024.0f) - mean * mean;
  float inv  = 1.0f / sqrtf(var + 1e-5f);
  float inv2 = inv * inv;

  float4 g4 = load4(gamma, (size_t)t * 4, f32);
  float4 b4 = load4(beta, (size_t)t * 4, f32);

  float m0 = (x0 - mean) * inv * g4.x + b4.x;
  float m1 = (x1 - mean) * inv * g4.y + b4.y;
  float m2 = (x2 - mean) * inv * g4.z + b4.z;
  float m3 = (x3 - mean) * inv * g4.w + b4.w;
  float v0 = s0 * g4.x * g4.x * inv2;
  float v1 = s1 * g4.y * g4.y * inv2;
  float v2 = s2 * g4.z * g4.z * inv2;
  float v3 = s3 * g4.w * g4.w * inv2;

  ushort4 omu = { f2b(m0), f2b(m1), f2b(m2), f2b(m3) };
  ushort4 oa1 = { f2b(m0*m0 + v0), f2b(m1*m1 + v1), f2b(m2*m2 + v2), f2b(m3*m3 + v3) };
  ushort4 osg = { f2b(v0), f2b(v1), f2b(v2), f2b(v3) };
  *(ushort4*)(mu_n + base) = omu;
  size_t r2 = (size_t)blockIdx.x * 2048 + (size_t)t * 4;
  *(ushort4*)(a1sg + r2) = oa1;
  *(ushort4*)(a1sg + r2 + 1024) = osg;
}

// ---------------------------------------------------------------- weight prep (fused)
__global__ __launch_bounds__(256) void wprep_kernel(
    const int* __restrict__ flag,
    const void* __restrict__ wq_mu, const void* __restrict__ wq_sraw,
    u16* __restrict__ q_bf, u16* __restrict__ q_s2,
    const void* __restrict__ wo_mu, const void* __restrict__ wo_sraw,
    u16* __restrict__ o_bf, u16* __restrict__ o_s2, int nq)
{
  const bool f32 = (*flag != 0);
  size_t idx = ((size_t)blockIdx.x * 256 + threadIdx.x) * 4;
  const void *wmu, *wsr; u16 *obf, *os2;
  if (idx < (size_t)nq) { wmu = wq_mu; wsr = wq_sraw; obf = q_bf; os2 = q_s2; }
  else { idx -= nq; wmu = wo_mu; wsr = wo_sraw; obf = o_bf; os2 = o_s2; }
  int row = (int)(idx >> 10), k = (int)(idx & 1023);
  float4 m4 = load4(wmu, idx, f32);
  float4 s4 = load4(wsr, idx, f32);
  float m[4] = { m4.x, m4.y, m4.z, m4.w };
  float s[4] = { s4.x, s4.y, s4.z, s4.w };
  ushort4 ob, os, oq;
  u16* obp = (u16*)&ob; u16* osp = (u16*)&os; u16* oqp = (u16*)&oq;
  #pragma unroll
  for (int i = 0; i < 4; ++i) {
    float sp = (s[i] > 15.f) ? s[i] : log1pf(__expf(s[i]));
    obp[i] = f2b(m[i]);
    osp[i] = f2b(sp);
    oqp[i] = f2b(m[i] * m[i]);
  }
  *(ushort4*)(obf + idx) = ob;
  size_t r2 = (size_t)row * 2048 + k;
  *(ushort4*)(os2 + r2) = os;
  *(ushort4*)(os2 + r2 + 1024) = oq;
}

// ---------------------------------------------------------------- paired GEMM (old 128^2, kept for output GEMM)
template<bool DYN>
__global__ __launch_bounds__(256, 4) void gemm_pair_kernel(
    const u16* __restrict__ A0, const u16* __restrict__ B0, int K0, void* C0, size_t ob0,
    const u16* __restrict__ A1, const u16* __restrict__ B1, int K1, void* C1, size_t ob1,
    int split, int N, const int* __restrict__ flag)
{
  __shared__ u16 lA[128 * 64];
  __shared__ u16 lB[128 * 64];
  const int t = threadIdx.x;
  int bx = blockIdx.x;
  const u16 *A, *B; void* C; size_t obase; int K;
  if (bx < split) { A = A0; B = B0; K = K0; C = C0; obase = ob0; }
  else { bx -= split; A = A1; B = B1; K = K1; C = C1; obase = ob1; }

  const int n0 = bx * 128, m0 = blockIdx.y * 128;
  const int lane = t & 63, wave = t >> 6;
  const int wr = (wave >> 1) * 64, wc = (wave & 1) * 64;
  const int m31 = lane & 31, h5 = lane >> 5;
  const int mx = m31 & 7;

  const int srow = t >> 3;
  const int gseg = (t & 7) ^ (srow & 7);

  f32x16 acc[2][2];
  #pragma unroll
  for (int i = 0; i < 2; ++i)
    #pragma unroll
    for (int j = 0; j < 2; ++j)
      #pragma unroll
      for (int r = 0; r < 16; ++r) acc[i][j][r] = 0.f;

  for (int k0 = 0; k0 < K; k0 += 64) {
    __syncthreads();
    #pragma unroll
    for (int rep = 0; rep < 4; ++rep) {
      gll16(A + (size_t)(m0 + srow + rep * 32) * K + k0 + gseg * 8,
            lA + rep * 2048 + wave * 512);
      gll16(B + (size_t)(n0 + srow + rep * 32) * K + k0 + gseg * 8,
            lB + rep * 2048 + wave * 512);
    }
    __syncthreads();
    #pragma unroll
    for (int ks = 0; ks < 4; ++ks) {
      const int seg = ks * 2 + h5;
      bf16x8 af[2], bfr[2];
      #pragma unroll
      for (int tm = 0; tm < 2; ++tm)
        af[tm] = *(const bf16x8*)&lA[(wr + tm * 32 + m31) * 64 + (seg ^ mx) * 8];
      #pragma unroll
      for (int tn = 0; tn < 2; ++tn)
        bfr[tn] = *(const bf16x8*)&lB[(wc + tn * 32 + m31) * 64 + (seg ^ mx) * 8];
      #pragma unroll
      for (int tm = 0; tm < 2; ++tm)
        #pragma unroll
        for (int tn = 0; tn < 2; ++tn)
          acc[tm][tn] = __builtin_amdgcn_mfma_f32_32x32x16_bf16(af[tm], bfr[tn], acc[tm][tn], 0, 0, 0);
    }
  }

  const bool of32 = DYN && (*flag != 0);
  #pragma unroll
  for (int tm = 0; tm < 2; ++tm)
    #pragma unroll
    for (int tn = 0; tn < 2; ++tn) {
      int colb = n0 + wc + tn * 32 + m31;
      #pragma unroll
      for (int r = 0; r < 16; ++r) {
        int row = m0 + wr + tm * 32 + (r & 3) + 8 * (r >> 2) + 4 * h5;
        float v = acc[tm][tn][r];
        size_t off = obase + (size_t)row * N + colb;
        if (DYN) {
          if (of32) ((float*)C)[off] = v;
          else      ((u16*)C)[off] = f2b(v);
        } else {
          ((u16*)C)[off] = f2b(v);
        }
      }
    }
}

// ---------------------------------------------------------------- paired GEMM (256^2, 8-phase counted-vmcnt, 32x32 MFMA)
// BM=BN=256, BK=64. 512 thr = 8 waves (2M x 4N), per-wave 128x64 out,
// 4mf x 2nf frags of 32x32x16 (2495 TF pipe vs 2075 for 16x16 [m06/m119]).
// Stage plan per tile T: P1/P2: A(T+1) halves; P3/P4: B(T+2) halves.
// vmcnt(4) at tile end (leaves B(T+2) 4 loads in flight). Jobs: sigma first
// (long jobs), per-class XCD swizzle (192 % 8 == 0, bijective), bm-fast decode.
#define SB __builtin_amdgcn_sched_barrier(0)
#define BARRIER do { SB; __builtin_amdgcn_s_barrier(); SB; } while (0)

__global__ __launch_bounds__(512, 2) void gemm8_pair_kernel(
    const u16* __restrict__ A0, const u16* __restrict__ B0, int K0, u16* __restrict__ C0,
    const u16* __restrict__ A1, const u16* __restrict__ B1, int K1, u16* __restrict__ C1,
    int split, int N)
{
  __shared__ u16 lA[2 * 256 * 64];
  __shared__ u16 lB[2 * 256 * 64];
  const int t = threadIdx.x;

  // job decode: class-local XCD swizzle, sigma (class 0) dispatches first
  int wgid = blockIdx.y * 24 + blockIdx.x;     // 384 total; 192 per class
  int job;
  if (wgid < 192) job = (wgid & 7) * 24 + (wgid >> 3);
  else { int w2 = wgid - 192; job = 192 + (w2 & 7) * 24 + (w2 >> 3); }

  const u16 *A, *B; u16* C; int K, jb;
  if (job < split) { A = A0; B = B0; K = K0; C = C0; jb = job; }
  else { A = A1; B = B1; K = K1; C = C1; jb = job - split; }
  const int bm = jb & 15, bn = jb >> 4;        // 16 m-tiles x 12 n-tiles
  const int m0 = bm * 256, n0 = bn * 256;
  const int NT = K >> 6;

  const int lane = t & 63, wave = t >> 6;
  const int wm = wave >> 2, wn = wave & 3;
  const int m31 = lane & 31, h5 = lane >> 5, mx = m31 & 7;

  // stage one 64-row x 64-col unit: 1 gll16 per wave (8 rows/wave)
  auto stg64 = [&](const u16* __restrict__ X, int row0, int k0, u16* ldsU) {
    int r = row0 + wave * 8 + (lane >> 3);
    int seg = (lane & 7) ^ ((lane >> 3) & 7);
    gll16(X + (size_t)r * K + k0 + seg * 8, ldsU + wave * 512);
  };

  const u16* rdA = lA + (wm * 128 + m31) * 64;   // + bo + mf*2048 + seg*8
  const u16* rdB = lB + (wn * 64 + m31) * 64;    // + bo + nf*2048 + seg*8

  f32x16 acc[4][2];
  #pragma unroll
  for (int i = 0; i < 4; ++i)
    #pragma unroll
    for (int j = 0; j < 2; ++j)
      #pragma unroll
      for (int r = 0; r < 16; ++r) acc[i][j][r] = 0.f;

  bf16x8 af[2][4];   // 2 m-frags (pair) x 4 k-chunks
  bf16x8 bf[2][4];   // 2 n-frags x 4 k-chunks (both live all tile)

  // prologue: A(T0), B(T0), B(T1)
  #pragma unroll
  for (int u = 0; u < 4; ++u) stg64(A, m0 + u * 64, 0, lA + u * 4096);
  #pragma unroll
  for (int u = 0; u < 4; ++u) stg64(B, n0 + u * 64, 0, lB + u * 4096);
  if (NT > 1) {
    #pragma unroll
    for (int u = 0; u < 4; ++u) stg64(B, n0 + u * 64, 64, lB + 16384 + u * 4096);
  }
  SB;
  asm volatile("s_waitcnt vmcnt(4)" ::: "memory");
  BARRIER;

  for (int T = 0; T < NT; ++T) {
    const int bo  = (T & 1) * 16384;
    const int bon = bo ^ 16384;
    const int kn  = (T + 1) * 64;
    const int kn2 = (T + 2) * 64;

    // -------- P1: read af(mf0,1) + bf[0]; stage A-h0(T+1); mfma col nf0
    #pragma unroll
    for (int mf = 0; mf < 2; ++mf)
      #pragma unroll
      for (int ks = 0; ks < 4; ++ks)
        af[mf][ks] = *(const bf16x8*)&rdA[bo + mf * 2048 + (((ks * 2 + h5)) ^ mx) * 8];
    #pragma unroll
    for (int ks = 0; ks < 4; ++ks)
      bf[0][ks] = *(const bf16x8*)&rdB[bo + (((ks * 2 + h5)) ^ mx) * 8];
    if (T + 1 < NT) {
      stg64(A, m0,      kn, lA + bon);
      stg64(A, m0 + 64, kn, lA + bon + 4096);
    }
    BARRIER;
    __builtin_amdgcn_s_setprio(1);
    #pragma unroll
    for (int mf = 0; mf < 2; ++mf)
      #pragma unroll
      for (int ks = 0; ks < 4; ++ks)
        acc[mf][0] = __builtin_amdgcn_mfma_f32_32x32x16_bf16(af[mf][ks], bf[0][ks], acc[mf][0], 0, 0, 0);
    __builtin_amdgcn_s_setprio(0);
    BARRIER;

    // -------- P2: read bf[1]; stage A-h1(T+1); mfma col nf1
    #pragma unroll
    for (int ks = 0; ks < 4; ++ks)
      bf[1][ks] = *(const bf16x8*)&rdB[bo + 2048 + (((ks * 2 + h5)) ^ mx) * 8];
    if (T + 1 < NT) {
      stg64(A, m0 + 128, kn, lA + bon + 8192);
      stg64(A, m0 + 192, kn, lA + bon + 12288);
    }
    BARRIER;
    __builtin_amdgcn_s_setprio(1);
    #pragma unroll
    for (int mf = 0; mf < 2; ++mf)
      #pragma unroll
      for (int ks = 0; ks < 4; ++ks)
        acc[mf][1] = __builtin_amdgcn_mfma_f32_32x32x16_bf16(af[mf][ks], bf[1][ks], acc[mf][1], 0, 0, 0);
    __builtin_amdgcn_s_setprio(0);
    BARRIER;

    // -------- P3: read af(mf2,3); stage B-h0(T+2); mfma col nf1
    #pragma unroll
    for (int mf = 0; mf < 2; ++mf)
      #pragma unroll
      for (int ks = 0; ks < 4; ++ks)
        af[mf][ks] = *(const bf16x8*)&rdA[bo + (2 + mf) * 2048 + (((ks * 2 + h5)) ^ mx) * 8];
    if (T + 2 < NT) {
      stg64(B, n0,      kn2, lB + bo);
      stg64(B, n0 + 64, kn2, lB + bo + 4096);
    }
    BARRIER;
    __builtin_amdgcn_s_setprio(1);
    #pragma unroll
    for (int mf = 0; mf < 2; ++mf)
      #pragma unroll
      for (int ks = 0; ks < 4; ++ks)
        acc[2 + mf][1] = __builtin_amdgcn_mfma_f32_32x32x16_bf16(af[mf][ks], bf[1][ks], acc[2 + mf][1], 0, 0, 0);
    __builtin_amdgcn_s_setprio(0);
    BARRIER;

    // -------- P4: stage B-h1(T+2); mfma col nf0; counted vmcnt
    if (T + 2 < NT) {
      stg64(B, n0 + 128, kn2, lB + bo + 8192);
      stg64(B, n0 + 192, kn2, lB + bo + 12288);
    }
    BARRIER;
    __builtin_amdgcn_s_setprio(1);
    #pragma unroll
    for (int mf = 0; mf < 2; ++mf)
      #pragma unroll
      for (int ks = 0; ks < 4; ++ks)
        acc[2 + mf][0] = __builtin_amdgcn_mfma_f32_32x32x16_bf16(af[mf][ks], bf[0][ks], acc[2 + mf][0], 0, 0, 0);
    __builtin_amdgcn_s_setprio(0);
    SB;
    if (T + 2 < NT) asm volatile("s_waitcnt vmcnt(4)" ::: "memory");
    else            asm volatile("s_waitcnt vmcnt(0)" ::: "memory");
    BARRIER;
  }

  // epilogue: 32x32 C/D layout: col=lane&31, row=(r&3)+8*(r>>2)+4*h5
  #pragma unroll
  for (int mf = 0; mf < 4; ++mf)
    #pragma unroll
    for (int nf = 0; nf < 2; ++nf) {
      int colb = n0 + wn * 64 + nf * 32 + m31;
      #pragma unroll
      for (int r = 0; r < 16; ++r) {
        int row = m0 + wm * 128 + mf * 32 + (r & 3) + 8 * (r >> 2) + 4 * h5;
        C[(size_t)row * N + colb] = f2b(acc[mf][nf][r]);
      }
    }
}

// ---------------------------------------------------------------- attention pass 1
__global__ __launch_bounds__(256) void attn_pass1(
    const u16* __restrict__ qkv_mu, float* __restrict__ invl)
{
  __shared__ u16 lK[128 * 72];
  const int t = threadIdx.x;
  const int wv = t >> 6, lane = t & 63;
  const int ml = lane & 15, qd = lane >> 4;
  const int bh = blockIdx.y;
  const int b = bh >> 4, h = bh & 15;
  const size_t rowbase = (size_t)b * 1024 * 3072;
  const int i0 = blockIdx.x * 64;
  const int qcol = h * 64, kcol = 1024 + h * 64;
  const int qrow = wv * 16;

  bf16x8 aQm[2];
  #pragma unroll
  for (int ks = 0; ks < 2; ++ks)
    aQm[ks] = *(const bf16x8*)(qkv_mu + rowbase +
        (size_t)(i0 + qrow + ml) * 3072 + qcol + ks * 32 + qd * 8);

  float lsum[4] = {0.f, 0.f, 0.f, 0.f};

  for (int j0 = 0; j0 < 1024; j0 += 128) {
    __syncthreads();
    #pragma unroll
    for (int rep = 0; rep < 4; ++rep) {
      int c = t + rep * 256;
      int row = c >> 3, seg = c & 7;
      *(uint4*)&lK[row * 72 + seg * 8] =
          *(const uint4*)(qkv_mu + rowbase + (size_t)(j0 + row) * 3072 + kcol + seg * 8);
    }
    __syncthreads();
    #pragma unroll
    for (int tj = 0; tj < 8; ++tj) {
      bf16x8 b0 = *(const bf16x8*)&lK[(tj * 16 + ml) * 72 + qd * 8];
      bf16x8 b1 = *(const bf16x8*)&lK[(tj * 16 + ml) * 72 + 32 + qd * 8];
      f32x4 s = (f32x4){0.f, 0.f, 0.f, 0.f};
      s = __builtin_amdgcn_mfma_f32_16x16x32_bf16(aQm[0], b0, s, 0, 0, 0);
      s = __builtin_amdgcn_mfma_f32_16x16x32_bf16(aQm[1], b1, s, 0, 0, 0);
      #pragma unroll
      for (int r = 0; r < 4; ++r) lsum[r] += __expf(s[r] * 0.125f);
    }
  }
  #pragma unroll
  for (int r = 0; r < 4; ++r) {
    float l = lsum[r];
    #pragma unroll
    for (int xo = 1; xo < 16; xo <<= 1) l += __shfl_xor(l, xo, 64);
    if (ml == 0)
      invl[(size_t)bh * 1024 + i0 + qrow + qd * 4 + r] = 1.0f / l;
  }
}

// ---------------------------------------------------------------- attention pass 2
__global__ __launch_bounds__(512, 4) void attn_pass2(
    const u16* __restrict__ qkv_mu, const u16* __restrict__ qkv_sg,
    const float* __restrict__ invl,
    u16* __restrict__ o_mu, u16* __restrict__ a1sgo)
{
  __shared__ u16 lKW[128 * 72];
  __shared__ u16 lV[128 * 72];
  __shared__ u16 lP[128 * 72];
  __shared__ u16 lW[128 * 72];

  const int t = threadIdx.x;
  const int wv = t >> 6, lane = t & 63;
  const int ml = lane & 15, qd = lane >> 4;
  const int bh = blockIdx.y;
  const int b = bh >> 4, h = bh & 15;
  const size_t rowbase = (size_t)b * 1024 * 3072;
  const int i0 = blockIdx.x * 128;
  const int qcol = h * 64, kcol = 1024 + h * 64, vcol = 2048 + h * 64;
  const int qrow = wv * 16;

  bf16x8 aQm[2], aQs[2];
  #pragma unroll
  for (int ks = 0; ks < 2; ++ks) {
    size_t ga = rowbase + (size_t)(i0 + qrow + ml) * 3072 + qcol + ks * 32 + qd * 8;
    aQm[ks] = *(const bf16x8*)(qkv_mu + ga);
    aQs[ks] = *(const bf16x8*)(qkv_sg + ga);
  }

  float lacc[4];
  #pragma unroll
  for (int r = 0; r < 4; ++r)
    lacc[r] = invl[(size_t)bh * 1024 + i0 + qrow + qd * 4 + r];

  f32x4 accm[4], accs[4];
  #pragma unroll
  for (int tj = 0; tj < 4; ++tj) {
    accm[tj] = (f32x4){0.f, 0.f, 0.f, 0.f};
    accs[tj] = (f32x4){0.f, 0.f, 0.f, 0.f};
  }

  for (int j0 = 0; j0 < 1024; j0 += 64) {
    __syncthreads();   // prev PV reads done before restaging
    #pragma unroll
    for (int rep = 0; rep < 2; ++rep) {
      int c = t + rep * 512;
      int row = c >> 3, seg = c & 7;
      const u16* src = (row < 64) ? qkv_mu : qkv_sg;
      int rr = row & 63;
      *(uint4*)&lKW[row * 72 + seg * 8] =
          *(const uint4*)(src + rowbase + (size_t)(j0 + rr) * 3072 + kcol + seg * 8);
    }
    {
      int buf = t >> 8, rem = t & 255;
      int db = rem >> 4, tb = rem & 15;
      const u16* src = buf ? qkv_sg : qkv_mu;
      ushort4 vals[4];
      #pragma unroll
      for (int i = 0; i < 4; ++i)
        vals[i] = *(const ushort4*)(src + rowbase + (size_t)(j0 + tb * 4 + i) * 3072 + vcol + db * 4);
      #pragma unroll
      for (int k = 0; k < 4; ++k) {
        ushort4 o;
        u16* op = (u16*)&o;
        const u16* v0 = (const u16*)&vals[0];
        const u16* v1 = (const u16*)&vals[1];
        const u16* v2 = (const u16*)&vals[2];
        const u16* v3 = (const u16*)&vals[3];
        op[0] = v0[k]; op[1] = v1[k]; op[2] = v2[k]; op[3] = v3[k];
        *(ushort4*)&lV[(buf * 64 + db * 4 + k) * 72 + tb * 4] = o;
      }
    }
    __syncthreads();

    f32x4 sm[4], ss[4];
    #pragma unroll
    for (int tj = 0; tj < 4; ++tj) {
      bf16x8 bm0 = *(const bf16x8*)&lKW[(tj * 16 + ml) * 72 + qd * 8];
      bf16x8 bm1 = *(const bf16x8*)&lKW[(tj * 16 + ml) * 72 + 32 + qd * 8];
      bf16x8 bs0 = *(const bf16x8*)&lKW[(64 + tj * 16 + ml) * 72 + qd * 8];
      bf16x8 bs1 = *(const bf16x8*)&lKW[(64 + tj * 16 + ml) * 72 + 32 + qd * 8];
      f32x4 s = (f32x4){0.f, 0.f, 0.f, 0.f};
      s = __builtin_amdgcn_mfma_f32_16x16x32_bf16(aQm[0], bm0, s, 0, 0, 0);
      s = __builtin_amdgcn_mfma_f32_16x16x32_bf16(aQm[1], bm1, s, 0, 0, 0);
      sm[tj] = s;
      f32x4 s2 = (f32x4){0.f, 0.f, 0.f, 0.f};
      s2 = __builtin_amdgcn_mfma_f32_16x16x32_bf16(aQs[0], bs0, s2, 0, 0, 0);
      s2 = __builtin_amdgcn_mfma_f32_16x16x32_bf16(aQs[1], bs1, s2, 0, 0, 0);
      ss[tj] = s2;
    }

    #pragma unroll
    for (int tj = 0; tj < 4; ++tj)
      #pragma unroll
      for (int r = 0; r < 4; ++r) {
        float p = __expf(sm[tj][r] * 0.125f) * lacc[r];
        float jp = p * (1.0f - p);
        float w = jp * jp * (ss[tj][r] * 0.125f);
        int row = qrow + qd * 4 + r;
        lP[row * 72 + tj * 16 + ml] = f2b(p);
        lW[row * 72 + tj * 16 + ml] = f2b(w);
      }
    __syncthreads();

    bf16x8 ap[2], aw[2];
    #pragma unroll
    for (int ks = 0; ks < 2; ++ks) {
      ap[ks] = *(const bf16x8*)&lP[(qrow + ml) * 72 + ks * 32 + qd * 8];
      aw[ks] = *(const bf16x8*)&lW[(qrow + ml) * 72 + ks * 32 + qd * 8];
    }
    #pragma unroll
    for (int tj = 0; tj < 4; ++tj) {
      bf16x8 vm0 = *(const bf16x8*)&lV[(tj * 16 + ml) * 72 + qd * 8];
      bf16x8 vm1 = *(const bf16x8*)&lV[(tj * 16 + ml) * 72 + 32 + qd * 8];
      bf16x8 vs0 = *(const bf16x8*)&lV[(64 + tj * 16 + ml) * 72 + qd * 8];
      bf16x8 vs1 = *(const bf16x8*)&lV[(64 + tj * 16 + ml) * 72 + 32 + qd * 8];
      accm[tj] = __builtin_amdgcn_mfma_f32_16x16x32_bf16(ap[0], vm0, accm[tj], 0, 0, 0);
      accm[tj] = __builtin_amdgcn_mfma_f32_16x16x32_bf16(ap[1], vm1, accm[tj], 0, 0, 0);
      accs[tj] = __builtin_amdgcn_mfma_f32_16x16x32_bf16(aw[0], vs0, accs[tj], 0, 0, 0);
      accs[tj] = __builtin_amdgcn_mfma_f32_16x16x32_bf16(aw[1], vs1, accs[tj], 0, 0, 0);
    }
  }

  // epilogue: o_mu [row][1024]; a1sgo [row][2048] = [mu^2+sg | sg]
  #pragma unroll
  for (int tj = 0; tj < 4; ++tj)
    #pragma unroll
    for (int r = 0; r < 4; ++r) {
      int row = i0 + qrow + qd * 4 + r;
      int col = h * 64 + tj * 16 + ml;
      size_t rowg = (size_t)b * 1024 + row;
      float om = accm[tj][r], os = accs[tj][r];
      o_mu[rowg * 1024 + col] = f2b(om);
      size_t r2 = rowg * 2048 + col;
      a1sgo[r2] = f2b(fmaf(om, om, os));
      a1sgo[r2 + 1024] = f2b(os);
    }
}

// ---------------------------------------------------------------- launch
extern "C" void kernel_launch(void* const* d_in, const int* in_sizes, int n_in,
                              void* d_out, int out_size, void* d_ws, size_t ws_size,
                              hipStream_t stream)
{
  (void)in_sizes; (void)n_in; (void)out_size; (void)ws_size;
  const void* mu        = d_in[0];
  const void* sigma     = d_in[1];
  const void* gamma     = d_in[2];
  const void* beta      = d_in[3];
  const void* wqkv_mu   = d_in[4];
  const void* wqkv_sraw = d_in[5];
  const void* wout_mu   = d_in[6];
  const void* wout_sraw = d_in[7];

  u16* ws = (u16*)d_ws;
  const size_t R = 4096;  // B*N
  u16* mu_n   = ws;                        // R*1024, reused as mu_o
  u16* a1sg   = mu_n + R * 1024;           // R*2048 [A1|sgn], reused as a1sgo
  u16* wq_bf  = a1sg + R * 2048;           // 3072*1024
  u16* wqs2   = wq_bf + 3072 * 1024;       // 3072*2048 [Wsig|Wmu^2]
  u16* wo_bf  = wqs2 + 3072 * 2048;        // 1024*1024
  u16* wos2   = wo_bf + 1024 * 1024;       // 1024*2048
  u16* mu_qkv = wos2 + 1024 * 2048;        // R*3072
  u16* sg_qkv = mu_qkv + R * 3072;         // R*3072
  int* flag   = (int*)(sg_qkv + R * 3072);
  float* invl = (float*)(flag + 16);       // 64*1024 floats

  u16* mu_o  = mu_n;
  u16* a1sgo = a1sg;

  detect_kernel<<<1, 256, 0, stream>>>((const u16*)sigma, flag);
  ln_prep_kernel<<<4096, 256, 0, stream>>>(flag, mu, sigma, gamma, beta, mu_n, a1sg);
  wprep_kernel<<<(4 * 1024 * 1024) / 1024, 256, 0, stream>>>(
      flag, wqkv_mu, wqkv_sraw, wq_bf, wqs2,
      wout_mu, wout_sraw, wo_bf, wos2, 3072 * 1024);

  // merged QKV GEMMs (256^2 8-phase, 32x32 MFMA): sigma first (K=2048), then mu
  gemm8_pair_kernel<<<dim3(24, 16), 512, 0, stream>>>(
      a1sg, wqs2, 2048, sg_qkv,
      mu_n, wq_bf, 1024, mu_qkv,
      192, 3072);

  attn_pass1<<<dim3(16, 64), 256, 0, stream>>>(mu_qkv, invl);
  attn_pass2<<<dim3(8, 64), 512, 0, stream>>>(mu_qkv, sg_qkv, invl, mu_o, a1sgo);

  // merged output GEMMs (old 128^2): mu (K=1024) + sigma (K=2048), N=1024
  gemm_pair_kernel<true><<<dim3(16, 32), 256, 0, stream>>>(
      mu_o, wo_bf, 1024, d_out, 0,
      a1sgo, wos2, 2048, d_out, R * 1024,
      8, 1024, flag);
}